// Round 12
// baseline (620.454 us; speedup 1.0000x reference)
//
#include <hip/hip_runtime.h>

#define BB 2
#define NN 20000
#define HH 128
#define EE 200000
#define EBLK 3125    // EE / 64
#define TILES 12500  // 2 halves x 2 batches x 3125 tiles
#define TPB 8        // tiles per block
#define EGRID 1563   // ceil(TILES / TPB)
#define NBLK 79      // ceil(NN/256)

typedef unsigned short u16;
typedef __attribute__((ext_vector_type(4))) float f32x4;
typedef __bf16 bf16x8 __attribute__((ext_vector_type(8)));

#define MFMA(a, b, c) __builtin_amdgcn_mfma_f32_16x16x32_bf16((a), (b), (c), 0, 0, 0)

__device__ __forceinline__ float bf2f(u16 u) {
    union { unsigned int i; float f; } v; v.i = ((unsigned int)u) << 16; return v.f;
}
__device__ __forceinline__ u16 f2bf(float f) {
    union { __bf16 h; u16 u; } v; v.h = (__bf16)f; return v.u;
}
#if __has_builtin(__builtin_amdgcn_rcpf)
__device__ __forceinline__ float rcpf(float x) { return __builtin_amdgcn_rcpf(x); }
#else
__device__ __forceinline__ float rcpf(float x) { return 1.f / x; }
#endif
__device__ __forceinline__ float silu_f(float z) { return z * rcpf(1.f + __expf(-z)); }
// flag-routed load (setup kernels only): f32 raw or bf16 raw
__device__ __forceinline__ float ldv(const void* p, long i, int f) {
    return f ? ((const float*)p)[i] : bf2f(((const u16*)p)[i]);
}

// ---------------- launch 1: dtype detection + cnt zeroing ----------------
__global__ __launch_bounds__(256) void detect_zero_kernel(const u16* __restrict__ f,
                                                          int* __restrict__ flag,
                                                          int* __restrict__ cnt) {
    int i = blockIdx.x * 256 + threadIdx.x;
    if (i < 40000) cnt[i] = 0;            // cnt_up | cnt_dn contiguous
    if (blockIdx.x == 0) {
        int tid = threadIdx.x;
        u16 v = f[tid * 2];
        int e = (v >> 7) & 0xFF;
        int ok = (e >= 101 && e <= 143) ? 1 : 0;
        __shared__ int c;
        if (tid == 0) c = 0;
        __syncthreads();
        atomicAdd(&c, ok);
        __syncthreads();
        if (tid == 0) *flag = (c < 200) ? 1 : 0;   // 1 => inputs are float32
    }
}

// ---------------- launch 2: fused setup ----------------
#define C5TOT 5281540
#define FTOT 180224
#define R0 5240000
#define R1 (R0 + C5TOT)
#define R2 (R1 + FTOT)
#define R3 (R2 + 2 * EE)
struct P18 { const void* p[18]; };
struct P8 { const void* w[8]; };

__global__ __launch_bounds__(256) void setup_kernel(
    P18 cp, P8 wf, const int* __restrict__ eu, const int* __restrict__ ed,
    float* __restrict__ ws_acc, u16* __restrict__ canon, u16* __restrict__ fbase,
    int* __restrict__ cnt_up, int* __restrict__ cnt_dn, const int* __restrict__ flag)
{
    long i = (long)blockIdx.x * 256 + threadIdx.x;
    if (i < R0) { ws_acc[i] = 0.f; return; }
    if (i < R1) {
        static const int off[19] = {
            0, 5120000, 5240000, 5260000, 5280000,
            5280128, 5280256, 5280384, 5280512, 5280640,
            5280642, 5280770, 5280898, 5281026, 5281154, 5281282,
            5281284, 5281412, 5281540 };
        static const int rsz[18] = {
            5120000, 120000, 20000, 20000,
            128, 128, 128, 128, 128, 1,
            128, 128, 128, 128, 128, 1,
            128, 128 };
        static const int soff[18] = {
            0, 0, 0, 0,
            32768, 0, 0, 0, 0, 0,
            32768, 0, 0, 0, 0, 0,
            0, 0 };
        int j = (int)(i - R0);
        int isf = *flag;
        int t = 0;
#pragma unroll 1
        while (j >= off[t + 1]) ++t;
        int k = j - off[t];
        u16 v = 0;
        if (k < rsz[t]) v = f2bf(ldv(cp.p[t], (long)soff[t] + k, isf));
        canon[j] = v;
        return;
    }
    if (i < R2) {
        static const int foff[9] = { 0, 32768, 49152, 65536, 98304, 114688,
                                     131072, 163840, 180224 };
        int j = (int)(i - R1);
        int isf = *flag;
        int t = 0;
#pragma unroll 1
        while (j >= foff[t + 1]) ++t;
        int m = j - foff[t];
        int jj = m & 7, lane = (m >> 3) & 63, nt = (m >> 9) & 7, kt = m >> 12;
        int k = kt * 32 + ((lane >> 4) * 8) + jj;
        int n = nt * 16 + (lane & 15);
        fbase[j] = f2bf(ldv(wf.w[t], (long)k * 128 + n, isf));
        return;
    }
    if (i < R3) {
        int e = (int)(i - R2);
        if (e < EE) atomicAdd(&cnt_up[eu[EE + e]], 1);
        else atomicAdd(&cnt_dn[ed[EE + e - EE]], 1);
    }
}

// ---------------- CSR scans + scatter ----------------
struct SP { const int* cnt[2]; int* cur[2]; int* bsum[2]; };

__global__ __launch_bounds__(256) void scan1_kernel(SP p) {
    int half = blockIdx.x / NBLK;
    int b = blockIdx.x - half * NBLK;
    int t = threadIdx.x;
    int i = b * 256 + t;
    __shared__ int buf[256];
    int v = (i < NN) ? p.cnt[half][i] : 0;
    buf[t] = v;
    __syncthreads();
    for (int s = 1; s < 256; s <<= 1) {
        int x = (t >= s) ? buf[t - s] : 0;
        __syncthreads();
        buf[t] += x;
        __syncthreads();
    }
    if (i < NN) p.cur[half][i] = buf[t] - v;   // exclusive within block
    if (t == 255) p.bsum[half][b] = buf[255];
}

__global__ __launch_bounds__(256) void scan2_kernel(int* __restrict__ bu, int* __restrict__ bd) {
    __shared__ int buf[2][128];
    int half = threadIdx.x >> 7, t = threadIdx.x & 127;
    int* bs = half ? bd : bu;
    int v = (t < NBLK) ? bs[t] : 0;
    buf[half][t] = v;
    __syncthreads();
    for (int s = 1; s < 128; s <<= 1) {
        int x = (t >= s) ? buf[half][t - s] : 0;
        __syncthreads();
        buf[half][t] += x;
        __syncthreads();
    }
    if (t < NBLK) bs[t] = buf[half][t] - v;    // exclusive block offsets
}

__global__ void scatter2_kernel(const int* __restrict__ eu, const int* __restrict__ ed,
                                int* __restrict__ cu, const int* __restrict__ bu,
                                int* __restrict__ cd, const int* __restrict__ bd,
                                int* __restrict__ su, int* __restrict__ sd) {
    int e = blockIdx.x * 256 + threadIdx.x;
    if (e < EE) {
        int d = eu[EE + e];
        int p = atomicAdd(&cu[d], 1) + bu[d >> 8];
        su[p] = e;
    } else {
        e -= EE;
        if (e < EE) {
            int d = ed[EE + e];
            int p = atomicAdd(&cd[d], 1) + bd[d >> 8];
            sd[p] = e;
        }
    }
}

// ---------------- edge kernel: 8 tiles/block, cross-tile pipelined ----------
struct EP {
    const int* eidx; const int* es; const u16* deg;
    const u16* fW1; const u16* fW2; const u16* fP1;
    const u16* w1last; const u16* bias1; const u16* bias2;
    const u16* biasp1; const u16* wp2; const u16* biasp2;
};

__global__ __launch_bounds__(512, 4) void edge_kernel(
    const u16* __restrict__ feat, const u16* __restrict__ posit,   // canonical bf16
    EP up, EP dn,
    float* __restrict__ msg_base, float* __restrict__ pos_base)
{
    const int tid = threadIdx.x;
    const int lane = tid & 63;
    const int wv = tid >> 6;              // 0..7 = n-tile
    const int tile0 = blockIdx.x * TPB;

    __shared__ u16 sX[2][64][136];
    __shared__ u16 sY[2][64][136];
    __shared__ float sRel[2][64][3];
    __shared__ float sDist[2][64];
    __shared__ float sInv[2][64];
    __shared__ int sDst[2][64];

    const int nt = wv;
    const int mrow = lane & 15;
    const int kq = (lane >> 4) * 8;
    const int crow = (lane >> 4) * 4;
    const int ccol = lane & 15;
    const int col = nt * 16 + ccol;
    const int gr = tid >> 3, gpart = tid & 7;   // gather role: 8 threads/row, 32B each

    // ---- prologue: fetch tile0 straight into buffer 0 ----
    {
        int tile = tile0;
        int half = tile / (2 * EBLK);
        int rem = tile - half * (2 * EBLK);
        int bb = rem / EBLK;
        int s0 = (rem - bb * EBLK) * 64;
        const EP Q = half ? dn : up;
        {
            int e = Q.es[s0 + gr];
            int s = Q.eidx[e];
            int d = Q.eidx[EE + e];
            const uint4* fs = (const uint4*)(feat + ((size_t)bb * NN + s) * HH);
            const uint4* fd = (const uint4*)(feat + ((size_t)bb * NN + d) * HH);
            *(uint4*)&sX[0][gr][gpart * 16] = fs[gpart * 2];
            *(uint4*)&sX[0][gr][gpart * 16 + 8] = fs[gpart * 2 + 1];
            *(uint4*)&sY[0][gr][gpart * 16] = fd[gpart * 2];
            *(uint4*)&sY[0][gr][gpart * 16 + 8] = fd[gpart * 2 + 1];
        }
        if (tid < 64) {
            int e = Q.es[s0 + tid];
            int s = Q.eidx[e];
            int d = Q.eidx[EE + e];
            sDst[0][tid] = d;
            sInv[0][tid] = 1.f / fmaxf(bf2f(Q.deg[d]), 1.f);
            const u16* ps = posit + ((size_t)bb * NN + s) * 3;
            const u16* pd = posit + ((size_t)bb * NN + d) * 3;
            float dx = bf2f(ps[0]) - bf2f(pd[0]);
            float dy = bf2f(ps[1]) - bf2f(pd[1]);
            float dz = bf2f(ps[2]) - bf2f(pd[2]);
            sRel[0][tid][0] = dx; sRel[0][tid][1] = dy; sRel[0][tid][2] = dz;
            sDist[0][tid] = sqrtf(dx * dx + dy * dy + dz * dz);
        }
    }

#pragma unroll 1
    for (int t = 0; t < TPB; ++t) {
        int tile = tile0 + t;
        const bool active = (tile < TILES);          // block-uniform
        if (!active) tile = TILES - 1;
        int half = tile / (2 * EBLK);
        int rem = tile - half * (2 * EBLK);
        int bb = rem / EBLK;
        const EP P = half ? dn : up;
        float* msg_acc = msg_base + (size_t)bb * NN * HH;
        float* pos_acc = pos_base + (size_t)bb * NN * 3;
        const int p = t & 1;

        __syncthreads();   // TOP: buffer p data visible; buffer p^1 free

        // ---- issue prefetch loads for tile t+1 (registers only) ----
        const bool dopre = (t < TPB - 1);            // block-uniform
        uint4 g0, g1, g2, g3;
        float m_rx = 0.f, m_ry = 0.f, m_rz = 0.f, m_dist = 0.f, m_inv = 0.f;
        int m_dst = 0;
        if (dopre) {
            int ntile = tile0 + t + 1;
            if (ntile >= TILES) ntile = TILES - 1;
            int nhalf = ntile / (2 * EBLK);
            int nrem = ntile - nhalf * (2 * EBLK);
            int nbb = nrem / EBLK;
            int ns0 = (nrem - nbb * EBLK) * 64;
            const EP Q = nhalf ? dn : up;
            {
                int e = Q.es[ns0 + gr];
                int s = Q.eidx[e];
                int d = Q.eidx[EE + e];
                const uint4* fs = (const uint4*)(feat + ((size_t)nbb * NN + s) * HH);
                const uint4* fd = (const uint4*)(feat + ((size_t)nbb * NN + d) * HH);
                g0 = fs[gpart * 2]; g1 = fs[gpart * 2 + 1];
                g2 = fd[gpart * 2]; g3 = fd[gpart * 2 + 1];
            }
            if (tid < 64) {
                int e = Q.es[ns0 + tid];
                int s = Q.eidx[e];
                int d = Q.eidx[EE + e];
                m_dst = d;
                m_inv = 1.f / fmaxf(bf2f(Q.deg[d]), 1.f);
                const u16* ps = posit + ((size_t)nbb * NN + s) * 3;
                const u16* pd = posit + ((size_t)nbb * NN + d) * 3;
                m_rx = bf2f(ps[0]) - bf2f(pd[0]);
                m_ry = bf2f(ps[1]) - bf2f(pd[1]);
                m_rz = bf2f(ps[2]) - bf2f(pd[2]);
                m_dist = sqrtf(m_rx * m_rx + m_ry * m_ry + m_rz * m_rz);
            }
        }

        f32x4 acc[4];
#pragma unroll
        for (int mt = 0; mt < 4; ++mt) acc[mt] = (f32x4){0.f, 0.f, 0.f, 0.f};

        // ----- msg layer 1 : [h_src | h_dst] @ W1[0:256]  (K=256) -----
#pragma unroll
        for (int kt = 0; kt < 8; ++kt) {
            const u16* Xb = (kt < 4) ? &sX[p][0][0] : &sY[p][0][0];
            const int kk = (kt & 3) * 32 + kq;
            bf16x8 bw = *(const bf16x8*)(P.fW1 + (size_t)(((kt * 8 + nt) * 64 + lane) * 8));
#pragma unroll
            for (int mt = 0; mt < 4; ++mt) {
                bf16x8 a = *(const bf16x8*)(Xb + (mt * 16 + mrow) * 136 + kk);
                acc[mt] = MFMA(a, bw, acc[mt]);
            }
        }
        __syncthreads();   // B2: all L1 reads of sX/sY done

        // ---- drain prefetch into buffer p^1 (visible at next TOP barrier) ----
        if (dopre) {
            const int q2 = p ^ 1;
            *(uint4*)&sX[q2][gr][gpart * 16] = g0;
            *(uint4*)&sX[q2][gr][gpart * 16 + 8] = g1;
            *(uint4*)&sY[q2][gr][gpart * 16] = g2;
            *(uint4*)&sY[q2][gr][gpart * 16 + 8] = g3;
            if (tid < 64) {
                sDst[q2][tid] = m_dst;
                sInv[q2][tid] = m_inv;
                sRel[q2][tid][0] = m_rx; sRel[q2][tid][1] = m_ry; sRel[q2][tid][2] = m_rz;
                sDist[q2][tid] = m_dist;
            }
        }

        // epilogue: + dist*W1[256] + b1, silu -> sX[p]
        {
            const float wl = bf2f(P.w1last[col]);
            const float bb2 = bf2f(P.bias1[col]);
#pragma unroll
            for (int mt = 0; mt < 4; ++mt) {
#pragma unroll
                for (int r = 0; r < 4; ++r) {
                    const int row = mt * 16 + crow + r;
                    float z = fmaf(sDist[p][row], wl, acc[mt][r]) + bb2;
                    sX[p][row][col] = f2bf(silu_f(z));
                }
            }
        }
        __syncthreads();   // B3

        // ----- msg layer 2 : sX @ W2 + b2 = messages -> sY (K=128) -----
#pragma unroll
        for (int mt = 0; mt < 4; ++mt) acc[mt] = (f32x4){0.f, 0.f, 0.f, 0.f};
#pragma unroll
        for (int kt = 0; kt < 4; ++kt) {
            const int kk = kt * 32 + kq;
            bf16x8 bw = *(const bf16x8*)(P.fW2 + (size_t)(((kt * 8 + nt) * 64 + lane) * 8));
#pragma unroll
            for (int mt = 0; mt < 4; ++mt) {
                bf16x8 a = *(const bf16x8*)(&sX[p][0][0] + (mt * 16 + mrow) * 136 + kk);
                acc[mt] = MFMA(a, bw, acc[mt]);
            }
        }
        {
            const float bb2 = bf2f(P.bias2[col]);
#pragma unroll
            for (int mt = 0; mt < 4; ++mt) {
#pragma unroll
                for (int r = 0; r < 4; ++r) {
                    const int row = mt * 16 + crow + r;
                    sY[p][row][col] = f2bf(acc[mt][r] + bb2);
                }
            }
        }
        __syncthreads();   // B4: messages visible; all reads of sX done

        // ----- pos layer 1 : silu(messages @ P1 + bp1) -> sX (K=128) -----
#pragma unroll
        for (int mt = 0; mt < 4; ++mt) acc[mt] = (f32x4){0.f, 0.f, 0.f, 0.f};
#pragma unroll
        for (int kt = 0; kt < 4; ++kt) {
            const int kk = kt * 32 + kq;
            bf16x8 bw = *(const bf16x8*)(P.fP1 + (size_t)(((kt * 8 + nt) * 64 + lane) * 8));
#pragma unroll
            for (int mt = 0; mt < 4; ++mt) {
                bf16x8 a = *(const bf16x8*)(&sY[p][0][0] + (mt * 16 + mrow) * 136 + kk);
                acc[mt] = MFMA(a, bw, acc[mt]);
            }
        }

        // segment-reduced scatter of messages (rows sorted by dst):
        // 512 threads = 128 cols x 4 row-spans of 16, pre-scaled by 1/clip(deg)
        if (active) {
            const int scol = tid & 127;
            const int r0 = (tid >> 7) * 16;
            float accv = 0.f;
            int dprev = sDst[p][r0];
            float invprev = sInv[p][r0];
#pragma unroll 1
            for (int r = r0; r < r0 + 16; ++r) {
                int dcur = sDst[p][r];
                if (dcur != dprev) {
                    unsafeAtomicAdd(&msg_acc[(size_t)dprev * HH + scol], accv * invprev);
                    accv = 0.f; dprev = dcur; invprev = sInv[p][r];
                }
                accv += bf2f(sY[p][r][scol]);
            }
            unsafeAtomicAdd(&msg_acc[(size_t)dprev * HH + scol], accv * invprev);
        }

        // pos1 epilogue -> sX[p]
        {
            const float bb2 = bf2f(P.biasp1[col]);
#pragma unroll
            for (int mt = 0; mt < 4; ++mt) {
#pragma unroll
                for (int r = 0; r < 4; ++r) {
                    const int row = mt * 16 + crow + r;
                    sX[p][row][col] = f2bf(silu_f(acc[mt][r] + bb2));
                }
            }
        }
        __syncthreads();   // B5

        // ----- pos layer 2 : tanh(hidden @ p2 + bp2) ; scatter wgt*rel_pos -----
        {
            const int r = tid >> 3, q = tid & 7;
            const unsigned* t32 = (const unsigned*)&sX[p][r][q * 16];
            const unsigned* w32 = (const unsigned*)(P.wp2 + q * 16);
            float pp = 0.f;
#pragma unroll
            for (int k = 0; k < 8; ++k) {
                unsigned a = t32[k], b = w32[k];
                union { unsigned i; float f; } al, ah, bl, bh;
                al.i = a << 16; ah.i = a & 0xffff0000u;
                bl.i = b << 16; bh.i = b & 0xffff0000u;
                pp = fmaf(al.f, bl.f, pp);
                pp = fmaf(ah.f, bh.f, pp);
            }
            pp += __shfl_xor(pp, 1);
            pp += __shfl_xor(pp, 2);
            pp += __shfl_xor(pp, 4);
            if (q == 0 && active) {
                float wgt = tanhf(pp + bf2f(P.biasp2[0]));
                const size_t pb = (size_t)sDst[p][r] * 3;
                unsafeAtomicAdd(&pos_acc[pb + 0], wgt * sRel[p][r][0]);
                unsafeAtomicAdd(&pos_acc[pb + 1], wgt * sRel[p][r][1]);
                unsafeAtomicAdd(&pos_acc[pb + 2], wgt * sRel[p][r][2]);
            }
        }
    }
}

// ---------------- update + fused pos output ----------------
__global__ __launch_bounds__(256) void update_kernel(
    const void* __restrict__ rawfeat, const void* __restrict__ rawpos,
    const u16* __restrict__ fU1, const u16* __restrict__ bu1,
    const u16* __restrict__ fU2, const u16* __restrict__ bu2,
    void* __restrict__ outp, const float* __restrict__ magg, const float* __restrict__ pacc,
    const int* __restrict__ flag)
{
    const int tid = threadIdx.x;
    const int lane = tid & 63;
    const int wv = tid >> 6;
    const int row0 = blockIdx.x * 64;
    const int isf = *flag;

    __shared__ u16 sA[64][136];   // features (bf16)
    __shared__ u16 sB[64][136];   // msg_acc -> hidden (reused)

    if (isf) {
        const float* fp = (const float*)rawfeat + (size_t)row0 * HH;
        for (int i = tid; i < 1024; i += 256) {
            int r = i >> 4, c = (i & 15) * 8;
            float4 v0 = *(const float4*)(fp + (size_t)r * HH + c);
            float4 v1 = *(const float4*)(fp + (size_t)r * HH + c + 4);
            uint4 o;
            o.x = (unsigned)f2bf(v0.x) | ((unsigned)f2bf(v0.y) << 16);
            o.y = (unsigned)f2bf(v0.z) | ((unsigned)f2bf(v0.w) << 16);
            o.z = (unsigned)f2bf(v1.x) | ((unsigned)f2bf(v1.y) << 16);
            o.w = (unsigned)f2bf(v1.z) | ((unsigned)f2bf(v1.w) << 16);
            *(uint4*)&sA[r][c] = o;
        }
    } else {
        const uint4* fp = (const uint4*)((const u16*)rawfeat + (size_t)row0 * HH);
        for (int i = tid; i < 1024; i += 256) {
            int r = i >> 4, c = i & 15;
            *(uint4*)&sA[r][c * 8] = fp[i];
        }
    }
    {
        const float4* am = (const float4*)(magg) + (size_t)row0 * 32;
        for (int i = tid; i < 2048; i += 256) {
            int r = i >> 5;
            float4 v = am[i];
            int c = (i & 31) * 4;
            sB[r][c + 0] = f2bf(v.x);
            sB[r][c + 1] = f2bf(v.y);
            sB[r][c + 2] = f2bf(v.z);
            sB[r][c + 3] = f2bf(v.w);
        }
    }
    __syncthreads();

    const int nt0 = wv * 2;
    const int mrow = lane & 15;
    const int kq = (lane >> 4) * 8;
    const int crow = (lane >> 4) * 4;
    const int ccol = lane & 15;

    f32x4 acc[4][2];
#pragma unroll
    for (int mt = 0; mt < 4; ++mt) {
        acc[mt][0] = (f32x4){0.f, 0.f, 0.f, 0.f};
        acc[mt][1] = (f32x4){0.f, 0.f, 0.f, 0.f};
    }
#pragma unroll
    for (int kt = 0; kt < 8; ++kt) {
        const u16* Xb = (kt < 4) ? &sA[0][0] : &sB[0][0];
        const int kk = (kt & 3) * 32 + kq;
        bf16x8 bw0 = *(const bf16x8*)(fU1 + (size_t)(((kt * 8 + nt0) * 64 + lane) * 8));
        bf16x8 bw1 = *(const bf16x8*)(fU1 + (size_t)(((kt * 8 + nt0 + 1) * 64 + lane) * 8));
#pragma unroll
        for (int mt = 0; mt < 4; ++mt) {
            bf16x8 a = *(const bf16x8*)(Xb + (mt * 16 + mrow) * 136 + kk);
            acc[mt][0] = MFMA(a, bw0, acc[mt][0]);
            acc[mt][1] = MFMA(a, bw1, acc[mt][1]);
        }
    }
    __syncthreads();

#pragma unroll
    for (int mt = 0; mt < 4; ++mt) {
#pragma unroll
        for (int n2 = 0; n2 < 2; ++n2) {
            const int col = (nt0 + n2) * 16 + ccol;
            const float bb = bf2f(bu1[col]);
#pragma unroll
            for (int r = 0; r < 4; ++r) {
                const int row = mt * 16 + crow + r;
                sB[row][col] = f2bf(silu_f(acc[mt][n2][r] + bb));
            }
        }
    }
    __syncthreads();

#pragma unroll
    for (int mt = 0; mt < 4; ++mt) {
        acc[mt][0] = (f32x4){0.f, 0.f, 0.f, 0.f};
        acc[mt][1] = (f32x4){0.f, 0.f, 0.f, 0.f};
    }
#pragma unroll
    for (int kt = 0; kt < 4; ++kt) {
        const int kk = kt * 32 + kq;
        bf16x8 bw0 = *(const bf16x8*)(fU2 + (size_t)(((kt * 8 + nt0) * 64 + lane) * 8));
        bf16x8 bw1 = *(const bf16x8*)(fU2 + (size_t)(((kt * 8 + nt0 + 1) * 64 + lane) * 8));
#pragma unroll
        for (int mt = 0; mt < 4; ++mt) {
            bf16x8 a = *(const bf16x8*)(&sB[0][0] + (mt * 16 + mrow) * 136 + kk);
            acc[mt][0] = MFMA(a, bw0, acc[mt][0]);
            acc[mt][1] = MFMA(a, bw1, acc[mt][1]);
        }
    }
#pragma unroll
    for (int mt = 0; mt < 4; ++mt) {
#pragma unroll
        for (int n2 = 0; n2 < 2; ++n2) {
            const int col = (nt0 + n2) * 16 + ccol;
            const float bb = bf2f(bu2[col]);
#pragma unroll
            for (int r = 0; r < 4; ++r) {
                const int row = mt * 16 + crow + r;
                const size_t idx = (size_t)(row0 + row) * HH + col;
                if (isf) {
                    float base = ((const float*)rawfeat)[idx];
                    ((float*)outp)[idx] = acc[mt][n2][r] + bb + base;
                } else {
                    float base = bf2f(sA[row][col]);
                    ((u16*)outp)[idx] = f2bf(acc[mt][n2][r] + bb + base);
                }
            }
        }
    }

    // fused positions output: 3 elems per node row (192 per block)
    if (tid < 192) {
        int i = row0 * 3 + tid;
        float x = pacc[i];
        if (isf) {
            float base = ((const float*)rawpos)[i];
            ((float*)outp)[5120000 + i] = base + 0.5f * x;
        } else {
            float base = bf2f(((const u16*)rawpos)[i]);
            ((u16*)outp)[5120000 + i] = f2bf(base + 0.5f * x);
        }
    }
}

extern "C" void kernel_launch(void* const* d_in, const int* in_sizes, int n_in,
                              void* d_out, int out_size, void* d_ws, size_t ws_size,
                              hipStream_t stream)
{
    // ws layout (bytes): identical to rounds 9-11
    float* ws_msg  = (float*)d_ws;
    float* ws_pos  = (float*)((char*)d_ws + 20480000);
    int*   cnt_up  = (int*)((char*)d_ws + 20960000);
    int*   cnt_dn  = (int*)((char*)d_ws + 21040000);
    int*   cur_up  = (int*)((char*)d_ws + 21120000);
    int*   cur_dn  = (int*)((char*)d_ws + 21200000);
    int*   bsum_up = (int*)((char*)d_ws + 21280000);
    int*   bsum_dn = (int*)((char*)d_ws + 21280400);
    int*   es_up   = (int*)((char*)d_ws + 21280800);
    int*   es_dn   = (int*)((char*)d_ws + 22080800);
    u16*   fbase   = (u16*)((char*)d_ws + 22880800);
    u16*   canon   = (u16*)((char*)d_ws + 23241248);
    int*   flag    = (int*)((char*)d_ws + 33804328);
    if (ws_size < 33804332ULL) return;

    u16* f_m1u = fbase;              // 32768 (K=256)
    u16* f_m2u = fbase + 32768;
    u16* f_p1u = fbase + 49152;
    u16* f_m1d = fbase + 65536;
    u16* f_m2d = fbase + 98304;
    u16* f_p1d = fbase + 114688;
    u16* f_u1  = fbase + 131072;
    u16* f_u2  = fbase + 163840;

    u16* cfeat  = canon;
    u16* cpos   = canon + 5120000;
    u16* cdgu   = canon + 5240000;
    u16* cdgd   = canon + 5260000;
    u16* cw1lu  = canon + 5280000;
    u16* cb1u   = canon + 5280128;
    u16* cb2u   = canon + 5280256;
    u16* cbp1u  = canon + 5280384;
    u16* cwp2u  = canon + 5280512;
    u16* cbp2u  = canon + 5280640;
    u16* cw1ld  = canon + 5280642;
    u16* cb1d   = canon + 5280770;
    u16* cb2d   = canon + 5280898;
    u16* cbp1d  = canon + 5281026;
    u16* cwp2d  = canon + 5281154;
    u16* cbp2d  = canon + 5281282;
    u16* cbu1   = canon + 5281284;
    u16* cbu2   = canon + 5281412;

    const int* ei_up = (const int*)d_in[2];
    const int* ei_dn = (const int*)d_in[3];

    // launch 1: detect dtype + zero CSR counters
    detect_zero_kernel<<<157, 256, 0, stream>>>((const u16*)d_in[0], flag, cnt_up);

    // launch 2: fused setup (ws zero | canon | frags | edge counts)
    P18 cp;
    cp.p[0] = d_in[0];  cp.p[1] = d_in[1];  cp.p[2] = d_in[4];  cp.p[3] = d_in[5];
    cp.p[4] = d_in[6];  cp.p[5] = d_in[7];  cp.p[6] = d_in[9];  cp.p[7] = d_in[11];
    cp.p[8] = d_in[12]; cp.p[9] = d_in[13];
    cp.p[10] = d_in[14]; cp.p[11] = d_in[15]; cp.p[12] = d_in[17]; cp.p[13] = d_in[19];
    cp.p[14] = d_in[20]; cp.p[15] = d_in[21];
    cp.p[16] = d_in[23]; cp.p[17] = d_in[25];
    P8 wsf;
    wsf.w[0] = d_in[6];  wsf.w[1] = d_in[8];  wsf.w[2] = d_in[10]; wsf.w[3] = d_in[14];
    wsf.w[4] = d_in[16]; wsf.w[5] = d_in[18]; wsf.w[6] = d_in[22]; wsf.w[7] = d_in[24];
    setup_kernel<<<(R3 + 255) / 256, 256, 0, stream>>>(cp, wsf, ei_up, ei_dn,
                                                       ws_msg, canon, fbase,
                                                       cnt_up, cnt_dn, flag);

    // launches 3-5: CSR scan + scatter
    SP sp;
    sp.cnt[0] = cnt_up; sp.cnt[1] = cnt_dn;
    sp.cur[0] = cur_up; sp.cur[1] = cur_dn;
    sp.bsum[0] = bsum_up; sp.bsum[1] = bsum_dn;
    scan1_kernel<<<2 * NBLK, 256, 0, stream>>>(sp);
    scan2_kernel<<<1, 256, 0, stream>>>(bsum_up, bsum_dn);
    scatter2_kernel<<<(2 * EE + 255) / 256, 256, 0, stream>>>(ei_up, ei_dn, cur_up, bsum_up,
                                                              cur_dn, bsum_dn, es_up, es_dn);

    // launch 6: pipelined edge kernel
    EP up, dn;
    up.eidx = ei_up; up.es = es_up; up.deg = cdgu;
    up.fW1 = f_m1u; up.fW2 = f_m2u; up.fP1 = f_p1u;
    up.w1last = cw1lu; up.bias1 = cb1u; up.bias2 = cb2u;
    up.biasp1 = cbp1u; up.wp2 = cwp2u; up.biasp2 = cbp2u;
    dn.eidx = ei_dn; dn.es = es_dn; dn.deg = cdgd;
    dn.fW1 = f_m1d; dn.fW2 = f_m2d; dn.fP1 = f_p1d;
    dn.w1last = cw1ld; dn.bias1 = cb1d; dn.bias2 = cb2d;
    dn.biasp1 = cbp1d; dn.wp2 = cwp2d; dn.biasp2 = cbp2d;
    edge_kernel<<<EGRID, 512, 0, stream>>>(cfeat, cpos, up, dn, ws_msg, ws_pos);

    // launch 7: update + positions out
    update_kernel<<<625, 256, 0, stream>>>(d_in[0], d_in[1], f_u1, cbu1, f_u2, cbu2,
                                           d_out, ws_msg, ws_pos, flag);
}

// Round 13
// 506.186 us; speedup vs baseline: 1.2257x; 1.2257x over previous
//
#include <hip/hip_runtime.h>

#define BB 2
#define NN 20000
#define HH 128
#define EE 200000
#define TR 128      // edge rows per block
#define NEB 1563    // ceil(EE/128)
#define NBLK 79     // ceil(NN/256)

typedef unsigned short u16;
typedef __attribute__((ext_vector_type(4))) float f32x4;
typedef __bf16 bf16x8 __attribute__((ext_vector_type(8)));

#define MFMA(a, b, c) __builtin_amdgcn_mfma_f32_16x16x32_bf16((a), (b), (c), 0, 0, 0)

__device__ __forceinline__ float bf2f(u16 u) {
    union { unsigned int i; float f; } v; v.i = ((unsigned int)u) << 16; return v.f;
}
__device__ __forceinline__ u16 f2bf(float f) {
    union { __bf16 h; u16 u; } v; v.h = (__bf16)f; return v.u;
}
#if __has_builtin(__builtin_amdgcn_rcpf)
__device__ __forceinline__ float rcpf(float x) { return __builtin_amdgcn_rcpf(x); }
#else
__device__ __forceinline__ float rcpf(float x) { return 1.f / x; }
#endif
__device__ __forceinline__ float silu_f(float z) { return z * rcpf(1.f + __expf(-z)); }
// flag-routed load (setup kernels only): f32 raw or bf16 raw
__device__ __forceinline__ float ldv(const void* p, long i, int f) {
    return f ? ((const float*)p)[i] : bf2f(((const u16*)p)[i]);
}

// ---------------- launch 1: dtype detection + cnt zeroing ----------------
__global__ __launch_bounds__(256) void detect_zero_kernel(const u16* __restrict__ f,
                                                          int* __restrict__ flag,
                                                          int* __restrict__ cnt) {
    int i = blockIdx.x * 256 + threadIdx.x;
    if (i < 40000) cnt[i] = 0;            // cnt_up | cnt_dn contiguous
    if (blockIdx.x == 0) {
        int tid = threadIdx.x;
        u16 v = f[tid * 2];
        int e = (v >> 7) & 0xFF;
        int ok = (e >= 101 && e <= 143) ? 1 : 0;
        __shared__ int c;
        if (tid == 0) c = 0;
        __syncthreads();
        atomicAdd(&c, ok);
        __syncthreads();
        if (tid == 0) *flag = (c < 200) ? 1 : 0;   // 1 => inputs are float32
    }
}

// ---------------- launch 2: fused setup ----------------
#define C5TOT 5281540
#define FTOT 180224
#define R0 5240000
#define R1 (R0 + C5TOT)
#define R2 (R1 + FTOT)
#define R3 (R2 + 2 * EE)
struct P18 { const void* p[18]; };
struct P8 { const void* w[8]; };

__global__ __launch_bounds__(256) void setup_kernel(
    P18 cp, P8 wf, const int* __restrict__ eu, const int* __restrict__ ed,
    float* __restrict__ ws_acc, u16* __restrict__ canon, u16* __restrict__ fbase,
    int* __restrict__ cnt_up, int* __restrict__ cnt_dn, const int* __restrict__ flag)
{
    long i = (long)blockIdx.x * 256 + threadIdx.x;
    if (i < R0) { ws_acc[i] = 0.f; return; }
    if (i < R1) {
        static const int off[19] = {
            0, 5120000, 5240000, 5260000, 5280000,
            5280128, 5280256, 5280384, 5280512, 5280640,
            5280642, 5280770, 5280898, 5281026, 5281154, 5281282,
            5281284, 5281412, 5281540 };
        static const int rsz[18] = {
            5120000, 120000, 20000, 20000,
            128, 128, 128, 128, 128, 1,
            128, 128, 128, 128, 128, 1,
            128, 128 };
        static const int soff[18] = {
            0, 0, 0, 0,
            32768, 0, 0, 0, 0, 0,
            32768, 0, 0, 0, 0, 0,
            0, 0 };
        int j = (int)(i - R0);
        int isf = *flag;
        int t = 0;
#pragma unroll 1
        while (j >= off[t + 1]) ++t;
        int k = j - off[t];
        u16 v = 0;
        if (k < rsz[t]) v = f2bf(ldv(cp.p[t], (long)soff[t] + k, isf));
        canon[j] = v;
        return;
    }
    if (i < R2) {
        static const int foff[9] = { 0, 32768, 49152, 65536, 98304, 114688,
                                     131072, 163840, 180224 };
        int j = (int)(i - R1);
        int isf = *flag;
        int t = 0;
#pragma unroll 1
        while (j >= foff[t + 1]) ++t;
        int m = j - foff[t];
        int jj = m & 7, lane = (m >> 3) & 63, nt = (m >> 9) & 7, kt = m >> 12;
        int k = kt * 32 + ((lane >> 4) * 8) + jj;
        int n = nt * 16 + (lane & 15);
        fbase[j] = f2bf(ldv(wf.w[t], (long)k * 128 + n, isf));
        return;
    }
    if (i < R3) {
        int e = (int)(i - R2);
        if (e < EE) atomicAdd(&cnt_up[eu[EE + e]], 1);
        else atomicAdd(&cnt_dn[ed[EE + e - EE]], 1);
    }
}

// ---------------- CSR scans + scatter ----------------
struct SP { const int* cnt[2]; int* cur[2]; int* bsum[2]; };

__global__ __launch_bounds__(256) void scan1_kernel(SP p) {
    int half = blockIdx.x / NBLK;
    int b = blockIdx.x - half * NBLK;
    int t = threadIdx.x;
    int i = b * 256 + t;
    __shared__ int buf[256];
    int v = (i < NN) ? p.cnt[half][i] : 0;
    buf[t] = v;
    __syncthreads();
    for (int s = 1; s < 256; s <<= 1) {
        int x = (t >= s) ? buf[t - s] : 0;
        __syncthreads();
        buf[t] += x;
        __syncthreads();
    }
    if (i < NN) p.cur[half][i] = buf[t] - v;   // exclusive within block
    if (t == 255) p.bsum[half][b] = buf[255];
}

__global__ __launch_bounds__(256) void scan2_kernel(int* __restrict__ bu, int* __restrict__ bd) {
    __shared__ int buf[2][128];
    int half = threadIdx.x >> 7, t = threadIdx.x & 127;
    int* bs = half ? bd : bu;
    int v = (t < NBLK) ? bs[t] : 0;
    buf[half][t] = v;
    __syncthreads();
    for (int s = 1; s < 128; s <<= 1) {
        int x = (t >= s) ? buf[half][t - s] : 0;
        __syncthreads();
        buf[half][t] += x;
        __syncthreads();
    }
    if (t < NBLK) bs[t] = buf[half][t] - v;    // exclusive block offsets
}

__global__ void scatter2_kernel(const int* __restrict__ eu, const int* __restrict__ ed,
                                int* __restrict__ cu, const int* __restrict__ bu,
                                int* __restrict__ cd, const int* __restrict__ bd,
                                int* __restrict__ su, int* __restrict__ sd) {
    int e = blockIdx.x * 256 + threadIdx.x;
    if (e < EE) {
        int d = eu[EE + e];
        int p = atomicAdd(&cu[d], 1) + bu[d >> 8];
        su[p] = e;
    } else {
        e -= EE;
        if (e < EE) {
            int d = ed[EE + e];
            int p = atomicAdd(&cd[d], 1) + bd[d >> 8];
            sd[p] = e;
        }
    }
}

// ---------------- edge kernel: 128 edge-rows per block ----------------
struct EP {
    const int* eidx; const int* es; const u16* deg;
    const u16* fW1; const u16* fW2; const u16* fP1;
    const u16* w1last; const u16* bias1; const u16* bias2;
    const u16* biasp1; const u16* wp2; const u16* biasp2;
};

__global__ __launch_bounds__(512, 4) void edge_kernel(
    const u16* __restrict__ feat, const u16* __restrict__ posit,   // canonical bf16
    EP up, EP dn,
    float* __restrict__ msg_base, float* __restrict__ pos_base)
{
    const int tid = threadIdx.x;
    const int lane = tid & 63;
    const int wv = tid >> 6;              // 0..7 = n-tile
    const int half = blockIdx.x / (BB * NEB);
    const int rem = blockIdx.x - half * (BB * NEB);
    const int bb = rem / NEB;
    const int s0 = (rem - bb * NEB) * TR;
    const EP P = half ? dn : up;
    float* msg_acc = msg_base + (size_t)bb * NN * HH;
    float* pos_acc = pos_base + (size_t)bb * NN * 3;

    __shared__ u16 sX[TR][136];   // h_src -> msg-hidden -> pos-hidden
    __shared__ u16 sY[TR][136];   // h_dst -> messages
    __shared__ float sRel[TR][3];
    __shared__ float sDist[TR];
    __shared__ float sInv[TR];
    __shared__ int sDst[TR];

    // meta (no barrier needed before gather: consumed only after B2/B4/B5)
    if (tid < TR) {
        int slot = s0 + tid; if (slot >= EE) slot = EE - 1;   // replicate last edge
        int e = P.es[slot];
        int s = P.eidx[e];
        int d = P.eidx[EE + e];
        sDst[tid] = d;
        sInv[tid] = 1.f / fmaxf(bf2f(P.deg[d]), 1.f);
        const u16* ps = posit + ((size_t)bb * NN + s) * 3;
        const u16* pd = posit + ((size_t)bb * NN + d) * 3;
        float dx = bf2f(ps[0]) - bf2f(pd[0]);
        float dy = bf2f(ps[1]) - bf2f(pd[1]);
        float dz = bf2f(ps[2]) - bf2f(pd[2]);
        sRel[tid][0] = dx; sRel[tid][1] = dy; sRel[tid][2] = dz;
        sDist[tid] = sqrtf(dx * dx + dy * dy + dz * dz);
    }

    // gather h_src -> sX, h_dst -> sY (4 threads/row, 64B each)
    {
        const int r = tid >> 2, part = tid & 3;
        int slot = s0 + r; if (slot >= EE) slot = EE - 1;
        int e = P.es[slot];
        int s = P.eidx[e];
        int d = P.eidx[EE + e];
        const uint4* fs = (const uint4*)(feat + ((size_t)bb * NN + s) * HH);
        const uint4* fd = (const uint4*)(feat + ((size_t)bb * NN + d) * HH);
        uint4* as = (uint4*)&sX[r][part * 32];
        uint4* ad = (uint4*)&sY[r][part * 32];
#pragma unroll
        for (int i = 0; i < 4; ++i) { as[i] = fs[part * 4 + i]; ad[i] = fd[part * 4 + i]; }
    }
    __syncthreads();   // B1

    const int nt = wv;
    const int mrow = lane & 15;
    const int kq = (lane >> 4) * 8;
    const int crow = (lane >> 4) * 4;
    const int ccol = lane & 15;
    const int col = nt * 16 + ccol;

    f32x4 acc[8];
#pragma unroll
    for (int mt = 0; mt < 8; ++mt) acc[mt] = (f32x4){0.f, 0.f, 0.f, 0.f};

    // ----- msg layer 1 : [h_src | h_dst] @ W1[0:256]  (K=256) -----
#pragma unroll
    for (int kt = 0; kt < 8; ++kt) {
        const u16* Xb = (kt < 4) ? &sX[0][0] : &sY[0][0];
        const int kk = (kt & 3) * 32 + kq;
        bf16x8 bw = *(const bf16x8*)(P.fW1 + (size_t)(((kt * 8 + nt) * 64 + lane) * 8));
#pragma unroll
        for (int mt = 0; mt < 8; ++mt) {
            bf16x8 a = *(const bf16x8*)(Xb + (mt * 16 + mrow) * 136 + kk);
            acc[mt] = MFMA(a, bw, acc[mt]);
        }
    }
    __syncthreads();   // B2: all L1 reads of sX/sY done

    // epilogue: + dist*W1[256] + b1, silu -> sX
    {
        const float wl = bf2f(P.w1last[col]);
        const float bb2 = bf2f(P.bias1[col]);
#pragma unroll
        for (int mt = 0; mt < 8; ++mt) {
#pragma unroll
            for (int r = 0; r < 4; ++r) {
                const int row = mt * 16 + crow + r;
                float z = fmaf(sDist[row], wl, acc[mt][r]) + bb2;
                sX[row][col] = f2bf(silu_f(z));
            }
        }
    }
    __syncthreads();   // B3

    // ----- msg layer 2 : sX @ W2 + b2 = messages -> sY (K=128) -----
#pragma unroll
    for (int mt = 0; mt < 8; ++mt) acc[mt] = (f32x4){0.f, 0.f, 0.f, 0.f};
#pragma unroll
    for (int kt = 0; kt < 4; ++kt) {
        const int kk = kt * 32 + kq;
        bf16x8 bw = *(const bf16x8*)(P.fW2 + (size_t)(((kt * 8 + nt) * 64 + lane) * 8));
#pragma unroll
        for (int mt = 0; mt < 8; ++mt) {
            bf16x8 a = *(const bf16x8*)(&sX[0][0] + (mt * 16 + mrow) * 136 + kk);
            acc[mt] = MFMA(a, bw, acc[mt]);
        }
    }
    {
        const float bb2 = bf2f(P.bias2[col]);
#pragma unroll
        for (int mt = 0; mt < 8; ++mt) {
#pragma unroll
            for (int r = 0; r < 4; ++r) {
                const int row = mt * 16 + crow + r;
                sY[row][col] = f2bf(acc[mt][r] + bb2);
            }
        }
    }
    __syncthreads();   // B4: messages visible; all reads of sX done

    // ----- pos layer 1 : silu(messages @ P1 + bp1) -> sX (K=128) -----
#pragma unroll
    for (int mt = 0; mt < 8; ++mt) acc[mt] = (f32x4){0.f, 0.f, 0.f, 0.f};
#pragma unroll
    for (int kt = 0; kt < 4; ++kt) {
        const int kk = kt * 32 + kq;
        bf16x8 bw = *(const bf16x8*)(P.fP1 + (size_t)(((kt * 8 + nt) * 64 + lane) * 8));
#pragma unroll
        for (int mt = 0; mt < 8; ++mt) {
            bf16x8 a = *(const bf16x8*)(&sY[0][0] + (mt * 16 + mrow) * 136 + kk);
            acc[mt] = MFMA(a, bw, acc[mt]);
        }
    }

    // segment-reduced scatter of messages (rows sorted by dst):
    // 512 threads = 128 cols x 4 row-spans of 32, pre-scaled by 1/clip(deg);
    // replicated tail rows (slot >= EE) contribute 0
    {
        const int scol = tid & 127;
        const int r0 = (tid >> 7) * 32;
        float accv = 0.f;
        int dprev = sDst[r0];
        float invprev = sInv[r0];
#pragma unroll 1
        for (int r = r0; r < r0 + 32; ++r) {
            int dcur = sDst[r];
            if (dcur != dprev) {
                unsafeAtomicAdd(&msg_acc[(size_t)dprev * HH + scol], accv * invprev);
                accv = 0.f; dprev = dcur; invprev = sInv[r];
            }
            float x = bf2f(sY[r][scol]);
            accv += (s0 + r < EE) ? x : 0.f;
        }
        unsafeAtomicAdd(&msg_acc[(size_t)dprev * HH + scol], accv * invprev);
    }

    // pos1 epilogue -> sX
    {
        const float bb2 = bf2f(P.biasp1[col]);
#pragma unroll
        for (int mt = 0; mt < 8; ++mt) {
#pragma unroll
            for (int r = 0; r < 4; ++r) {
                const int row = mt * 16 + crow + r;
                sX[row][col] = f2bf(silu_f(acc[mt][r] + bb2));
            }
        }
    }
    __syncthreads();   // B5

    // ----- pos layer 2 : tanh(hidden @ p2 + bp2) ; scatter wgt*rel_pos -----
    {
        const int r = tid >> 2, q = tid & 3;   // 4 threads/row, 32 cols each
        const unsigned* t32 = (const unsigned*)&sX[r][q * 32];
        const unsigned* w32 = (const unsigned*)(P.wp2 + q * 32);
        float p = 0.f;
#pragma unroll
        for (int k = 0; k < 16; ++k) {
            unsigned a = t32[k], b = w32[k];
            union { unsigned i; float f; } al, ah, bl, bh;
            al.i = a << 16; ah.i = a & 0xffff0000u;
            bl.i = b << 16; bh.i = b & 0xffff0000u;
            p = fmaf(al.f, bl.f, p);
            p = fmaf(ah.f, bh.f, p);
        }
        p += __shfl_xor(p, 1);
        p += __shfl_xor(p, 2);
        if (q == 0 && s0 + r < EE) {
            float wgt = tanhf(p + bf2f(P.biasp2[0]));
            const size_t pb = (size_t)sDst[r] * 3;
            unsafeAtomicAdd(&pos_acc[pb + 0], wgt * sRel[r][0]);
            unsafeAtomicAdd(&pos_acc[pb + 1], wgt * sRel[r][1]);
            unsafeAtomicAdd(&pos_acc[pb + 2], wgt * sRel[r][2]);
        }
    }
}

// ---------------- update + fused pos output ----------------
__global__ __launch_bounds__(256) void update_kernel(
    const void* __restrict__ rawfeat, const void* __restrict__ rawpos,
    const u16* __restrict__ fU1, const u16* __restrict__ bu1,
    const u16* __restrict__ fU2, const u16* __restrict__ bu2,
    void* __restrict__ outp, const float* __restrict__ magg, const float* __restrict__ pacc,
    const int* __restrict__ flag)
{
    const int tid = threadIdx.x;
    const int lane = tid & 63;
    const int wv = tid >> 6;
    const int row0 = blockIdx.x * 64;
    const int isf = *flag;

    __shared__ u16 sA[64][136];   // features (bf16)
    __shared__ u16 sB[64][136];   // msg_acc -> hidden (reused)

    if (isf) {
        const float* fp = (const float*)rawfeat + (size_t)row0 * HH;
        for (int i = tid; i < 1024; i += 256) {
            int r = i >> 4, c = (i & 15) * 8;
            float4 v0 = *(const float4*)(fp + (size_t)r * HH + c);
            float4 v1 = *(const float4*)(fp + (size_t)r * HH + c + 4);
            uint4 o;
            o.x = (unsigned)f2bf(v0.x) | ((unsigned)f2bf(v0.y) << 16);
            o.y = (unsigned)f2bf(v0.z) | ((unsigned)f2bf(v0.w) << 16);
            o.z = (unsigned)f2bf(v1.x) | ((unsigned)f2bf(v1.y) << 16);
            o.w = (unsigned)f2bf(v1.z) | ((unsigned)f2bf(v1.w) << 16);
            *(uint4*)&sA[r][c] = o;
        }
    } else {
        const uint4* fp = (const uint4*)((const u16*)rawfeat + (size_t)row0 * HH);
        for (int i = tid; i < 1024; i += 256) {
            int r = i >> 4, c = i & 15;
            *(uint4*)&sA[r][c * 8] = fp[i];
        }
    }
    {
        const float4* am = (const float4*)(magg) + (size_t)row0 * 32;
        for (int i = tid; i < 2048; i += 256) {
            int r = i >> 5;
            float4 v = am[i];
            int c = (i & 31) * 4;
            sB[r][c + 0] = f2bf(v.x);
            sB[r][c + 1] = f2bf(v.y);
            sB[r][c + 2] = f2bf(v.z);
            sB[r][c + 3] = f2bf(v.w);
        }
    }
    __syncthreads();

    const int nt0 = wv * 2;
    const int mrow = lane & 15;
    const int kq = (lane >> 4) * 8;
    const int crow = (lane >> 4) * 4;
    const int ccol = lane & 15;

    f32x4 acc[4][2];
#pragma unroll
    for (int mt = 0; mt < 4; ++mt) {
        acc[mt][0] = (f32x4){0.f, 0.f, 0.f, 0.f};
        acc[mt][1] = (f32x4){0.f, 0.f, 0.f, 0.f};
    }
#pragma unroll
    for (int kt = 0; kt < 8; ++kt) {
        const u16* Xb = (kt < 4) ? &sA[0][0] : &sB[0][0];
        const int kk = (kt & 3) * 32 + kq;
        bf16x8 bw0 = *(const bf16x8*)(fU1 + (size_t)(((kt * 8 + nt0) * 64 + lane) * 8));
        bf16x8 bw1 = *(const bf16x8*)(fU1 + (size_t)(((kt * 8 + nt0 + 1) * 64 + lane) * 8));
#pragma unroll
        for (int mt = 0; mt < 4; ++mt) {
            bf16x8 a = *(const bf16x8*)(Xb + (mt * 16 + mrow) * 136 + kk);
            acc[mt][0] = MFMA(a, bw0, acc[mt][0]);
            acc[mt][1] = MFMA(a, bw1, acc[mt][1]);
        }
    }
    __syncthreads();

#pragma unroll
    for (int mt = 0; mt < 4; ++mt) {
#pragma unroll
        for (int n2 = 0; n2 < 2; ++n2) {
            const int col = (nt0 + n2) * 16 + ccol;
            const float bb = bf2f(bu1[col]);
#pragma unroll
            for (int r = 0; r < 4; ++r) {
                const int row = mt * 16 + crow + r;
                sB[row][col] = f2bf(silu_f(acc[mt][n2][r] + bb));
            }
        }
    }
    __syncthreads();

#pragma unroll
    for (int mt = 0; mt < 4; ++mt) {
        acc[mt][0] = (f32x4){0.f, 0.f, 0.f, 0.f};
        acc[mt][1] = (f32x4){0.f, 0.f, 0.f, 0.f};
    }
#pragma unroll
    for (int kt = 0; kt < 4; ++kt) {
        const int kk = kt * 32 + kq;
        bf16x8 bw0 = *(const bf16x8*)(fU2 + (size_t)(((kt * 8 + nt0) * 64 + lane) * 8));
        bf16x8 bw1 = *(const bf16x8*)(fU2 + (size_t)(((kt * 8 + nt0 + 1) * 64 + lane) * 8));
#pragma unroll
        for (int mt = 0; mt < 4; ++mt) {
            bf16x8 a = *(const bf16x8*)(&sB[0][0] + (mt * 16 + mrow) * 136 + kk);
            acc[mt][0] = MFMA(a, bw0, acc[mt][0]);
            acc[mt][1] = MFMA(a, bw1, acc[mt][1]);
        }
    }
#pragma unroll
    for (int mt = 0; mt < 4; ++mt) {
#pragma unroll
        for (int n2 = 0; n2 < 2; ++n2) {
            const int col = (nt0 + n2) * 16 + ccol;
            const float bb = bf2f(bu2[col]);
#pragma unroll
            for (int r = 0; r < 4; ++r) {
                const int row = mt * 16 + crow + r;
                const size_t idx = (size_t)(row0 + row) * HH + col;
                if (isf) {
                    float base = ((const float*)rawfeat)[idx];
                    ((float*)outp)[idx] = acc[mt][n2][r] + bb + base;
                } else {
                    float base = bf2f(sA[row][col]);
                    ((u16*)outp)[idx] = f2bf(acc[mt][n2][r] + bb + base);
                }
            }
        }
    }

    // fused positions output: 3 elems per node row (192 per block)
    if (tid < 192) {
        int i = row0 * 3 + tid;
        float x = pacc[i];
        if (isf) {
            float base = ((const float*)rawpos)[i];
            ((float*)outp)[5120000 + i] = base + 0.5f * x;
        } else {
            float base = bf2f(((const u16*)rawpos)[i]);
            ((u16*)outp)[5120000 + i] = f2bf(base + 0.5f * x);
        }
    }
}

extern "C" void kernel_launch(void* const* d_in, const int* in_sizes, int n_in,
                              void* d_out, int out_size, void* d_ws, size_t ws_size,
                              hipStream_t stream)
{
    // ws layout (bytes): identical to round 9/10
    float* ws_msg  = (float*)d_ws;
    float* ws_pos  = (float*)((char*)d_ws + 20480000);
    int*   cnt_up  = (int*)((char*)d_ws + 20960000);
    int*   cnt_dn  = (int*)((char*)d_ws + 21040000);
    int*   cur_up  = (int*)((char*)d_ws + 21120000);
    int*   cur_dn  = (int*)((char*)d_ws + 21200000);
    int*   bsum_up = (int*)((char*)d_ws + 21280000);
    int*   bsum_dn = (int*)((char*)d_ws + 21280400);
    int*   es_up   = (int*)((char*)d_ws + 21280800);
    int*   es_dn   = (int*)((char*)d_ws + 22080800);
    u16*   fbase   = (u16*)((char*)d_ws + 22880800);
    u16*   canon   = (u16*)((char*)d_ws + 23241248);
    int*   flag    = (int*)((char*)d_ws + 33804328);
    if (ws_size < 33804332ULL) return;

    u16* f_m1u = fbase;              // 32768 (K=256)
    u16* f_m2u = fbase + 32768;
    u16* f_p1u = fbase + 49152;
    u16* f_m1d = fbase + 65536;
    u16* f_m2d = fbase + 98304;
    u16* f_p1d = fbase + 114688;
    u16* f_u1  = fbase + 131072;
    u16* f_u2  = fbase + 163840;

    u16* cfeat  = canon;
    u16* cpos   = canon + 5120000;
    u16* cdgu   = canon + 5240000;
    u16* cdgd   = canon + 5260000;
    u16* cw1lu  = canon + 5280000;
    u16* cb1u   = canon + 5280128;
    u16* cb2u   = canon + 5280256;
    u16* cbp1u  = canon + 5280384;
    u16* cwp2u  = canon + 5280512;
    u16* cbp2u  = canon + 5280640;
    u16* cw1ld  = canon + 5280642;
    u16* cb1d   = canon + 5280770;
    u16* cb2d   = canon + 5280898;
    u16* cbp1d  = canon + 5281026;
    u16* cwp2d  = canon + 5281154;
    u16* cbp2d  = canon + 5281282;
    u16* cbu1   = canon + 5281284;
    u16* cbu2   = canon + 5281412;

    const int* ei_up = (const int*)d_in[2];
    const int* ei_dn = (const int*)d_in[3];

    // launch 1: detect dtype + zero CSR counters
    detect_zero_kernel<<<157, 256, 0, stream>>>((const u16*)d_in[0], flag, cnt_up);

    // launch 2: fused setup (ws zero | canon | frags | edge counts)
    P18 cp;
    cp.p[0] = d_in[0];  cp.p[1] = d_in[1];  cp.p[2] = d_in[4];  cp.p[3] = d_in[5];
    cp.p[4] = d_in[6];  cp.p[5] = d_in[7];  cp.p[6] = d_in[9];  cp.p[7] = d_in[11];
    cp.p[8] = d_in[12]; cp.p[9] = d_in[13];
    cp.p[10] = d_in[14]; cp.p[11] = d_in[15]; cp.p[12] = d_in[17]; cp.p[13] = d_in[19];
    cp.p[14] = d_in[20]; cp.p[15] = d_in[21];
    cp.p[16] = d_in[23]; cp.p[17] = d_in[25];
    P8 wsf;
    wsf.w[0] = d_in[6];  wsf.w[1] = d_in[8];  wsf.w[2] = d_in[10]; wsf.w[3] = d_in[14];
    wsf.w[4] = d_in[16]; wsf.w[5] = d_in[18]; wsf.w[6] = d_in[22]; wsf.w[7] = d_in[24];
    setup_kernel<<<(R3 + 255) / 256, 256, 0, stream>>>(cp, wsf, ei_up, ei_dn,
                                                       ws_msg, canon, fbase,
                                                       cnt_up, cnt_dn, flag);

    // launches 3-5: CSR scan + scatter
    SP sp;
    sp.cnt[0] = cnt_up; sp.cnt[1] = cnt_dn;
    sp.cur[0] = cur_up; sp.cur[1] = cur_dn;
    sp.bsum[0] = bsum_up; sp.bsum[1] = bsum_dn;
    scan1_kernel<<<2 * NBLK, 256, 0, stream>>>(sp);
    scan2_kernel<<<1, 256, 0, stream>>>(bsum_up, bsum_dn);
    scatter2_kernel<<<(2 * EE + 255) / 256, 256, 0, stream>>>(ei_up, ei_dn, cur_up, bsum_up,
                                                              cur_dn, bsum_dn, es_up, es_dn);

    // launch 6: edge kernel (128 rows/block)
    EP up, dn;
    up.eidx = ei_up; up.es = es_up; up.deg = cdgu;
    up.fW1 = f_m1u; up.fW2 = f_m2u; up.fP1 = f_p1u;
    up.w1last = cw1lu; up.bias1 = cb1u; up.bias2 = cb2u;
    up.biasp1 = cbp1u; up.wp2 = cwp2u; up.biasp2 = cbp2u;
    dn.eidx = ei_dn; dn.es = es_dn; dn.deg = cdgd;
    dn.fW1 = f_m1d; dn.fW2 = f_m2d; dn.fP1 = f_p1d;
    dn.w1last = cw1ld; dn.bias1 = cb1d; dn.bias2 = cb2d;
    dn.biasp1 = cbp1d; dn.wp2 = cwp2d; dn.biasp2 = cbp2d;
    edge_kernel<<<2 * BB * NEB, 512, 0, stream>>>(cfeat, cpos, up, dn, ws_msg, ws_pos);

    // launch 7: update + positions out
    update_kernel<<<625, 256, 0, stream>>>(d_in[0], d_in[1], f_u1, cbu1, f_u2, cbu2,
                                           d_out, ws_msg, ws_pos, flag);
}